// Round 4
// baseline (375.076 us; speedup 1.0000x reference)
//
#include <hip/hip_runtime.h>

#define IMG_H 128
#define IMG_W 128
#define OUT_H 127   // valid conv output rows
#define OUT_W 127   // valid conv output cols

// ---------------------------------------------------------------------------
// Kernel 1: one block per HALF image (top: input rows 0..64, bottom: 64..127).
// Stage the half into LDS with 8 independent float4 loads per thread (deep
// MLP -> HBM BW-bound, not latency-bound), then compute
// sum(sigmoid(conv2x2+bias)) for the half's output rows from LDS with
// register row-rotation.  Partial sums -> part[2b+h].
// LDS = 65*128*4 = 33,280 B -> 4 blocks/CU, 16 waves/CU.
// ---------------------------------------------------------------------------
__global__ __launch_bounds__(256) void conv_sig_sum_kernel(
    const float* __restrict__ data,
    const float* __restrict__ conv_w,
    const float* __restrict__ conv_b,
    float* __restrict__ part)          // [2*B] partial sums
{
    __shared__ float tile[65 * IMG_W];

    const int bid  = blockIdx.x;
    const int b    = bid >> 1;
    const int h    = bid & 1;
    const int tid  = threadIdx.x;
    const int wid  = tid >> 6;
    const int lane = tid & 63;

    const int nrows = h ? 64 : 65;      // staged input rows
    const int nout  = h ? 63 : 64;      // output rows computed by this block

    // ---- stage half-image into LDS (coalesced float4, all loads independent)
    const float* src  = data + (size_t)b * (IMG_H * IMG_W) + (h * 64) * IMG_W;
    const float4* src4 = (const float4*)src;
    float4* t4 = (float4*)tile;

    float4 v[8];
    #pragma unroll
    for (int j = 0; j < 8; ++j) v[j] = src4[tid + j * 256];   // covers 2048 float4
    #pragma unroll
    for (int j = 0; j < 8; ++j) t4[tid + j * 256] = v[j];
    if (h == 0 && tid < 32) t4[2048 + tid] = src4[2048 + tid]; // tail row 64 (n4=2080)

    __syncthreads();

    // ---- compute from LDS
    const float w00 = conv_w[0], w01 = conv_w[1];
    const float w10 = conv_w[2], w11 = conv_w[3];
    const float bias = conv_b[0];

    const int rs = wid * 16;                 // local output row start
    const int re = min(rs + 16, nout);       // wave 3 of h=1 gets 15 rows

    float acc = 0.f;

    const float* rowt = tile + rs * IMG_W;
    float t0  = rowt[lane];
    float t0n = rowt[lane + 1];
    float t1  = rowt[64 + lane];
    float t1n = (lane < 63) ? rowt[65 + lane] : 0.f;

    for (int r = rs; r < re; ++r) {
        const float* rowb = tile + (r + 1) * IMG_W;
        float b0  = rowb[lane];
        float b0n = rowb[lane + 1];
        float b1  = rowb[64 + lane];
        float b1n = (lane < 63) ? rowb[65 + lane] : 0.f;

        // output col = lane (0..63, always < 127)
        {
            float vv = fmaf(w00, t0, fmaf(w01, t0n, fmaf(w10, b0, fmaf(w11, b0n, bias))));
            float e = __expf(-vv);
            acc += __builtin_amdgcn_rcpf(1.0f + e);
        }
        // output col = 64+lane (valid while <= 126)
        if (lane < 63) {
            float vv = fmaf(w00, t1, fmaf(w01, t1n, fmaf(w10, b1, fmaf(w11, b1n, bias))));
            float e = __expf(-vv);
            acc += __builtin_amdgcn_rcpf(1.0f + e);
        }

        t0 = b0; t0n = b0n; t1 = b1; t1n = b1n;
    }

    // ---- block reduction
    #pragma unroll
    for (int off = 32; off > 0; off >>= 1)
        acc += __shfl_down(acc, off, 64);

    __shared__ float wsum[4];
    if (lane == 0) wsum[wid] = acc;
    __syncthreads();
    if (tid == 0)
        part[bid] = wsum[0] + wsum[1] + wsum[2] + wsum[3];
}

// ---------------------------------------------------------------------------
// Kernel 2: tiny head.  part[8192] -> per-image means -> [2048,2] -> 4
// tanh-affine layers -> final linear -> sum of squares -> exp(-gamma*s).
// ---------------------------------------------------------------------------
__global__ __launch_bounds__(256) void fraud_head_kernel(
    const float* __restrict__ part,      // [8192]
    const float* __restrict__ fraud_W,   // [4,2,2]
    const float* __restrict__ fraud_b,   // [4,2]
    const float* __restrict__ scale,     // [4,2]
    const float* __restrict__ shift,     // [4,2]
    const float* __restrict__ final_W,   // [1,2]
    const float* __restrict__ final_b,   // [1]
    float* __restrict__ out)
{
    const int tid = threadIdx.x;
    const float inv_npix = 1.0f / (float)(OUT_H * OUT_W);

    float ssq = 0.f;
    for (int r = tid; r < 2048; r += 256) {
        float x0 = (part[4 * r + 0] + part[4 * r + 1]) * inv_npix;  // image 2r
        float x1 = (part[4 * r + 2] + part[4 * r + 3]) * inv_npix;  // image 2r+1
        #pragma unroll
        for (int l = 0; l < 4; ++l) {
            float a00 = fraud_W[l * 4 + 0], a01 = fraud_W[l * 4 + 1];
            float a10 = fraud_W[l * 4 + 2], a11 = fraud_W[l * 4 + 3];
            float y0 = tanhf(fmaf(x0, a00, fmaf(x1, a01, fraud_b[l * 2 + 0])))
                           * scale[l * 2 + 0] + shift[l * 2 + 0];
            float y1 = tanhf(fmaf(x0, a10, fmaf(x1, a11, fraud_b[l * 2 + 1])))
                           * scale[l * 2 + 1] + shift[l * 2 + 1];
            x0 = y0; x1 = y1;
        }
        float o = fmaf(x0, final_W[0], fmaf(x1, final_W[1], final_b[0]));
        ssq += o * o;
    }

    #pragma unroll
    for (int off = 32; off > 0; off >>= 1)
        ssq += __shfl_down(ssq, off, 64);

    __shared__ float wsum[4];
    const int wid = tid >> 6, lane = tid & 63;
    if (lane == 0) wsum[wid] = ssq;
    __syncthreads();
    if (tid == 0) {
        float total = wsum[0] + wsum[1] + wsum[2] + wsum[3];
        out[0] = __expf(-1e-4f * total);
    }
}

// ---------------------------------------------------------------------------
extern "C" void kernel_launch(void* const* d_in, const int* in_sizes, int n_in,
                              void* d_out, int out_size, void* d_ws, size_t ws_size,
                              hipStream_t stream) {
    const float* data    = (const float*)d_in[0];
    const float* conv_w  = (const float*)d_in[1];
    const float* conv_b  = (const float*)d_in[2];
    const float* fraud_W = (const float*)d_in[3];
    const float* fraud_b = (const float*)d_in[4];
    const float* scale   = (const float*)d_in[5];
    const float* shift   = (const float*)d_in[6];
    const float* final_W = (const float*)d_in[7];
    const float* final_b = (const float*)d_in[8];
    float* out  = (float*)d_out;
    float* part = (float*)d_ws;          // 8192 floats, fully rewritten each call

    conv_sig_sum_kernel<<<8192, 256, 0, stream>>>(data, conv_w, conv_b, part);
    fraud_head_kernel<<<1, 256, 0, stream>>>(part, fraud_W, fraud_b,
                                             scale, shift, final_W, final_b, out);
}